// Round 14
// baseline (449.425 us; speedup 1.0000x reference)
//
#include <hip/hip_runtime.h>
#include <hip/hip_cooperative_groups.h>
#include <math.h>

namespace cg = cooperative_groups;

#define N_NODES_C 100000
#define N_EDGES_C 3200000
#define NB 782        // ceil(100000 / 128) buckets of 128 nodes
#define BNODES 128
#define LDS_CAP 6144  // per-bucket LDS staging capacity (mean ~4092, +32 sigma)
#define CHUNK 8192    // edges per partition block
#define NBLK 391      // ceil(N_EDGES_C / CHUNK)
#define NSCAN (NB * NBLK)              // 305,762
#define NBLK_SCAN ((NSCAN + 1023) / 1024)  // 299

typedef unsigned short u16;
typedef __attribute__((ext_vector_type(8))) short short8v;   // 8 bf16 = 4 VGPR
typedef __attribute__((ext_vector_type(4))) float float4v;   // mfma accumulator

__device__ __forceinline__ float bf2f(u16 u) {
    unsigned int t = ((unsigned int)u) << 16;
    return __uint_as_float(t);
}
__device__ __forceinline__ u16 f2bf(float f) {  // round-to-nearest-even
    unsigned int x = __float_as_uint(f);
    x += 0x7fffu + ((x >> 16) & 1u);
    return (u16)(x >> 16);
}

// ============ cooperative CSR partition: hist + scan + boffs + scatter in ONE kernel ============

__global__ __launch_bounds__(256) void csr_coop_kernel(const int* __restrict__ src,
                                                       const int* __restrict__ dst,
                                                       int* __restrict__ cnt,
                                                       int* __restrict__ bsums,
                                                       int* __restrict__ boffs,
                                                       int* __restrict__ offs,
                                                       unsigned int* __restrict__ stage,
                                                       int n_edges) {
    cg::grid_group grid = cg::this_grid();
    __shared__ unsigned int spack[CHUNK];   // 32 KB
    __shared__ int hist[NB];
    __shared__ int lcur[NB];
    __shared__ int tsum[256];
    const int blk = blockIdx.x, tid = threadIdx.x;
    const int e0 = blk * CHUNK;
    const int cntE = min(CHUNK, n_edges - e0);

    // ---- P1: per-chunk histogram -> cnt[bucket*NBLK + blk] ----
    for (int b = tid; b < NB; b += 256) hist[b] = 0;
    __syncthreads();
    for (int i = tid * 4; i < cntE; i += 1024) {
        int4 d4 = *(const int4*)&dst[e0 + i];
        atomicAdd(&hist[d4.x >> 7], 1); atomicAdd(&hist[d4.y >> 7], 1);
        atomicAdd(&hist[d4.z >> 7], 1); atomicAdd(&hist[d4.w >> 7], 1);
    }
    __syncthreads();
    for (int i = tid; i < NB; i += 256) cnt[i * NBLK + blk] = hist[i];
    grid.sync();

    // ---- P2: per-1024-chunk inclusive scan of cnt, block sums -> bsums ----
    if (blk < NBLK_SCAN) {
        int base = blk * 1024 + tid * 4;
        int v[4];
#pragma unroll
        for (int i = 0; i < 4; ++i) v[i] = (base + i < NSCAN) ? cnt[base + i] : 0;
        int ts = v[0] + v[1] + v[2] + v[3];
        tsum[tid] = ts;
        __syncthreads();
        for (int off = 1; off < 256; off <<= 1) {
            int t = (tid >= off) ? tsum[tid - off] : 0;
            __syncthreads();
            tsum[tid] += t;
            __syncthreads();
        }
        int run = tsum[tid] - ts;
#pragma unroll
        for (int i = 0; i < 4; ++i) {
            run += v[i];
            if (base + i < NSCAN) cnt[base + i] = run;
        }
        if (tid == 255) bsums[blk] = tsum[255];
    }
    grid.sync();

    // ---- P3: exclusive scan of bsums[0..NBLK_SCAN) by block 0 (2 elems/thread) ----
    if (blk == 0) {
        int i0 = tid * 2, i1 = tid * 2 + 1;
        int e0v = (i0 < NBLK_SCAN) ? bsums[i0] : 0;
        int e1v = (i1 < NBLK_SCAN) ? bsums[i1] : 0;
        int ps = e0v + e1v;
        tsum[tid] = ps;
        __syncthreads();
        for (int off = 1; off < 256; off <<= 1) {
            int t = (tid >= off) ? tsum[tid - off] : 0;
            __syncthreads();
            tsum[tid] += t;
            __syncthreads();
        }
        int ex = tsum[tid] - ps;
        if (i0 < NBLK_SCAN) bsums[i0] = ex;
        if (i1 < NBLK_SCAN) bsums[i1] = ex + e0v;
    }
    grid.sync();

    // ---- P4: add block offsets; emit boffs at bucket boundaries ----
    if (blk < NBLK_SCAN) {
        int base = blk * 1024 + tid * 4;
        int add = bsums[blk];
#pragma unroll
        for (int i = 0; i < 4; ++i) {
            int idx = base + i;
            if (idx < NSCAN) {
                int v = cnt[idx] + add;
                cnt[idx] = v;
                if (((idx + 1) % NBLK) == 0) {
                    int b = (idx + 1) / NBLK;   // 1..NB
                    boffs[b] = v;
                    if (b == NB) offs[N_NODES_C] = v;
                }
            }
        }
        if (blk == 0 && tid == 0) boffs[0] = 0;
    }
    grid.sync();

    // ---- P5: scatter into bucket-sorted stage (LDS counting sort) ----
    for (int b = tid; b < NB; b += 256) hist[b] = 0;
    __syncthreads();
    for (int i = tid * 4; i < cntE; i += 1024) {
        int4 d4 = *(const int4*)&dst[e0 + i];
        atomicAdd(&hist[d4.x >> 7], 1); atomicAdd(&hist[d4.y >> 7], 1);
        atomicAdd(&hist[d4.z >> 7], 1); atomicAdd(&hist[d4.w >> 7], 1);
    }
    __syncthreads();
    {
        int loc[4];
        const int bi = tid * 4;
        int s = 0;
#pragma unroll
        for (int k = 0; k < 4; ++k) {
            int idx = bi + k;
            loc[k] = (idx < NB) ? hist[idx] : 0;
            s += loc[k];
        }
        tsum[tid] = s;
        __syncthreads();
        for (int off = 1; off < 256; off <<= 1) {
            int t = (tid >= off) ? tsum[tid - off] : 0;
            __syncthreads();
            tsum[tid] += t;
            __syncthreads();
        }
        int run = tsum[tid] - s;
#pragma unroll
        for (int k = 0; k < 4; ++k) {
            int idx = bi + k;
            if (idx < NB) {
                int h = loc[k];
                hist[idx] = run;
                lcur[idx] = run;
                run += h;
            }
        }
    }
    __syncthreads();
    for (int i = tid * 4; i < cntE; i += 1024) {
        int4 d4 = *(const int4*)&dst[e0 + i];
        int4 s4 = *(const int4*)&src[e0 + i];
        int p;
        p = atomicAdd(&lcur[d4.x >> 7], 1); spack[p] = (unsigned)s4.x | (((unsigned)d4.x & 127u) << 17);
        p = atomicAdd(&lcur[d4.y >> 7], 1); spack[p] = (unsigned)s4.y | (((unsigned)d4.y & 127u) << 17);
        p = atomicAdd(&lcur[d4.z >> 7], 1); spack[p] = (unsigned)s4.z | (((unsigned)d4.z & 127u) << 17);
        p = atomicAdd(&lcur[d4.w >> 7], 1); spack[p] = (unsigned)s4.w | (((unsigned)d4.w & 127u) << 17);
    }
    __syncthreads();
    for (int b = tid; b < NB; b += 256) {
        int l0 = hist[b];
        int l1 = (b + 1 < NB) ? hist[b + 1] : cntE;
        int idx = b * NBLK + blk;
        int g0 = idx ? cnt[idx - 1] : 0;
        for (int j = l0; j < l1; ++j) stage[g0 + (j - l0)] = spack[j];
    }
}

__global__ __launch_bounds__(256) void bucket_finalize_kernel(const unsigned int* __restrict__ stage,
                                                              const int* __restrict__ boffs,
                                                              int* __restrict__ offs,
                                                              int* __restrict__ srcs) {
    __shared__ int hist[BNODES];
    __shared__ int excl[BNODES];
    __shared__ int curs[BNODES];
    __shared__ int sbuf[LDS_CAP];
    const int b = blockIdx.x, tid = threadIdx.x;
    const int base = boffs[b];
    const int count = boffs[b + 1] - base;
    const int n0 = b * BNODES;
    for (int i = tid; i < BNODES; i += 256) hist[i] = 0;
    __syncthreads();
    for (int i = tid; i < count; i += 256) {
        unsigned int w = stage[base + i];
        atomicAdd(&hist[w >> 17], 1);
    }
    __syncthreads();
    if (tid < BNODES) excl[tid] = hist[tid];
    __syncthreads();
    for (int off = 1; off < BNODES; off <<= 1) {
        int t = 0;
        if (tid < BNODES && tid >= off) t = excl[tid - off];
        __syncthreads();
        if (tid < BNODES) excl[tid] += t;
        __syncthreads();
    }
    if (tid < BNODES) {
        int ex = excl[tid] - hist[tid];
        int n = n0 + tid;
        if (n < N_NODES_C) offs[n] = base + ex;
        curs[tid] = ex;
    }
    __syncthreads();
    if (count <= LDS_CAP) {
        for (int i = tid; i < count; i += 256) {
            unsigned int w = stage[base + i];
            int p = atomicAdd(&curs[w >> 17], 1);
            sbuf[p] = (int)(w & 0x1FFFFu);
        }
        __syncthreads();
        for (int i = tid; i < count; i += 256) srcs[base + i] = sbuf[i];
    } else {
        for (int i = tid; i < count; i += 256) {
            unsigned int w = stage[base + i];
            int p = atomicAdd(&curs[w >> 17], 1);
            srcs[base + p] = (int)(w & 0x1FFFFu);
        }
    }
}

// ====== gather64v: bf16 in, bf16 out; 16 lanes/row, 4 row-slots/wave, 32-row unroll ======

__global__ __launch_bounds__(256) void gather64v_kernel(const u16* __restrict__ feat,
                                                        const int* __restrict__ offs,
                                                        const int* __restrict__ srcs,
                                                        const float* __restrict__ bias,
                                                        u16* __restrict__ out, int n_nodes) {
    const int wave = threadIdx.x >> 6;
    const int lane = threadIdx.x & 63;
    const int grp  = lane >> 4;
    const int cl   = lane & 15;
    const int n = blockIdx.x * 4 + wave;
    if (n >= n_nodes) return;

    float a0 = 0.f, a1 = 0.f, a2 = 0.f, a3 = 0.f;
    if (grp == 0) {
        ushort4 v = *(const ushort4*)&feat[(size_t)n * 64 + cl * 4];
        a0 = bf2f(v.x); a1 = bf2f(v.y); a2 = bf2f(v.z); a3 = bf2f(v.w);
    }
    const int s0 = offs[n], s1 = offs[n + 1];
    int i = s0;
    for (; i + 32 <= s1; i += 32) {
        int r[8];
#pragma unroll
        for (int u = 0; u < 8; ++u) r[u] = srcs[i + u * 4 + grp];
        ushort4 v[8];
#pragma unroll
        for (int u = 0; u < 8; ++u) v[u] = *(const ushort4*)&feat[(size_t)r[u] * 64 + cl * 4];
#pragma unroll
        for (int u = 0; u < 8; ++u) {
            a0 += bf2f(v[u].x); a1 += bf2f(v[u].y); a2 += bf2f(v[u].z); a3 += bf2f(v[u].w);
        }
    }
    for (; i + 8 <= s1; i += 8) {
        int ra = srcs[i + grp];
        int rb = srcs[i + 4 + grp];
        ushort4 va = *(const ushort4*)&feat[(size_t)ra * 64 + cl * 4];
        ushort4 vb = *(const ushort4*)&feat[(size_t)rb * 64 + cl * 4];
        a0 += bf2f(va.x); a1 += bf2f(va.y); a2 += bf2f(va.z); a3 += bf2f(va.w);
        a0 += bf2f(vb.x); a1 += bf2f(vb.y); a2 += bf2f(vb.z); a3 += bf2f(vb.w);
    }
    for (; i + 4 <= s1; i += 4) {
        int rr = srcs[i + grp];
        ushort4 v = *(const ushort4*)&feat[(size_t)rr * 64 + cl * 4];
        a0 += bf2f(v.x); a1 += bf2f(v.y); a2 += bf2f(v.z); a3 += bf2f(v.w);
    }
    if (i + grp < s1) {
        int rr = srcs[i + grp];
        ushort4 v = *(const ushort4*)&feat[(size_t)rr * 64 + cl * 4];
        a0 += bf2f(v.x); a1 += bf2f(v.y); a2 += bf2f(v.z); a3 += bf2f(v.w);
    }
    a0 += __shfl_xor(a0, 16); a1 += __shfl_xor(a1, 16);
    a2 += __shfl_xor(a2, 16); a3 += __shfl_xor(a3, 16);
    a0 += __shfl_xor(a0, 32); a1 += __shfl_xor(a1, 32);
    a2 += __shfl_xor(a2, 32); a3 += __shfl_xor(a3, 32);
    if (lane < 16) {
        float4 b = *(const float4*)&bias[cl * 4];
        ushort4 o;
        o.x = f2bf(fmaxf(a0 + b.x, 0.f));
        o.y = f2bf(fmaxf(a1 + b.y, 0.f));
        o.z = f2bf(fmaxf(a2 + b.z, 0.f));
        o.w = f2bf(fmaxf(a3 + b.w, 0.f));
        *(ushort4*)&out[(size_t)n * 64 + cl * 4] = o;
    }
}

// ====== MFMA dense128: out_bf16 = bf16(x) @ bf16(W1)  (W1 frags in LDS; x converted in-reg) ======
// A-fragment: lane l, elem i <- A[l&15][kt*32+(l>>4)*8+i]; D: row=(l>>4)*4+r, col=l&15

__global__ __launch_bounds__(256) void mfma_dense128_kernel(const float* __restrict__ in,
                                                            const float* __restrict__ W,
                                                            u16* __restrict__ out, int n_nodes) {
    __shared__ u16 w1f[16 * 512];   // 16 frags (kt 0..3, jt 0..3) x 512, 16 KB
    const int tid = threadIdx.x;
    for (int idx = tid; idx < 8192; idx += 256) {
        int frag = idx >> 9;          // kt*4+jt
        int within = idx & 511;
        int lane = within >> 3;
        int i = within & 7;
        int kt = frag >> 2, jt = frag & 3;
        int k = kt * 32 + (lane >> 4) * 8 + i;
        int j = jt * 16 + (lane & 15);
        w1f[idx] = f2bf(W[k * 64 + j]);
    }
    __syncthreads();
    const int w = tid >> 6, l = tid & 63;
    const int nbase = blockIdx.x * 64 + w * 16;
    const int arow = min(nbase + (l & 15), n_nodes - 1);
    short8v a[4];
#pragma unroll
    for (int kt = 0; kt < 4; ++kt) {
        float4 f0 = *(const float4*)&in[(size_t)arow * 128 + kt * 32 + (l >> 4) * 8];
        float4 f1 = *(const float4*)&in[(size_t)arow * 128 + kt * 32 + (l >> 4) * 8 + 4];
        short8v t;
        t[0] = (short)f2bf(f0.x); t[1] = (short)f2bf(f0.y);
        t[2] = (short)f2bf(f0.z); t[3] = (short)f2bf(f0.w);
        t[4] = (short)f2bf(f1.x); t[5] = (short)f2bf(f1.y);
        t[6] = (short)f2bf(f1.z); t[7] = (short)f2bf(f1.w);
        a[kt] = t;
    }
#pragma unroll
    for (int jt = 0; jt < 4; ++jt) {
        float4v acc = {0.f, 0.f, 0.f, 0.f};
#pragma unroll
        for (int kt = 0; kt < 4; ++kt)
            acc = __builtin_amdgcn_mfma_f32_16x16x32_bf16(a[kt], *(short8v*)&w1f[(kt * 4 + jt) * 512 + l * 8], acc, 0, 0, 0);
#pragma unroll
        for (int r = 0; r < 4; ++r) {
            int n = nbase + (l >> 4) * 4 + r;
            if (n < n_nodes) out[(size_t)n * 64 + jt * 16 + (l & 15)] = f2bf(acc[r]);
        }
    }
}

// ====== MFMA fused: T = relu(in@W2+b2); out_bf16 = T@W3 ======

__global__ __launch_bounds__(256) void mfma_w2w3_kernel(const u16* __restrict__ in,
                                                        const float* __restrict__ W2,
                                                        const float* __restrict__ b2,
                                                        const float* __restrict__ W3,
                                                        u16* __restrict__ out, int n_nodes) {
    __shared__ u16 w2f[4096];
    __shared__ u16 w3f[4096];
    __shared__ u16 sT[64 * 72];
    const int tid = threadIdx.x;
    for (int idx = tid; idx < 4096; idx += 256) {
        int frag = idx >> 9;
        int within = idx & 511;
        int lane = within >> 3;
        int i = within & 7;
        int kt = frag >> 2, jt = frag & 3;
        int k = kt * 32 + (lane >> 4) * 8 + i;
        int j = jt * 16 + (lane & 15);
        w2f[idx] = f2bf(W2[k * 64 + j]);
        w3f[idx] = f2bf(W3[k * 64 + j]);
    }
    __syncthreads();
    const int w = tid >> 6, l = tid & 63;
    const int nbase = blockIdx.x * 64 + w * 16;
    const int arow = min(nbase + (l & 15), n_nodes - 1);
    short8v a0 = *(const short8v*)&in[(size_t)arow * 64 + (l >> 4) * 8];
    short8v a1 = *(const short8v*)&in[(size_t)arow * 64 + 32 + (l >> 4) * 8];
#pragma unroll
    for (int jt = 0; jt < 4; ++jt) {
        float bv = b2[jt * 16 + (l & 15)];
        float4v acc = {bv, bv, bv, bv};
        acc = __builtin_amdgcn_mfma_f32_16x16x32_bf16(a0, *(short8v*)&w2f[(0 * 4 + jt) * 512 + l * 8], acc, 0, 0, 0);
        acc = __builtin_amdgcn_mfma_f32_16x16x32_bf16(a1, *(short8v*)&w2f[(1 * 4 + jt) * 512 + l * 8], acc, 0, 0, 0);
#pragma unroll
        for (int r = 0; r < 4; ++r) {
            int row = w * 16 + (l >> 4) * 4 + r;
            sT[row * 72 + jt * 16 + (l & 15)] = f2bf(fmaxf(acc[r], 0.f));
        }
    }
    __syncthreads();
    const int trow = w * 16 + (l & 15);
    short8v t0 = *(short8v*)&sT[trow * 72 + (l >> 4) * 8];
    short8v t1 = *(short8v*)&sT[trow * 72 + 32 + (l >> 4) * 8];
#pragma unroll
    for (int jt = 0; jt < 4; ++jt) {
        float4v acc = {0.f, 0.f, 0.f, 0.f};
        acc = __builtin_amdgcn_mfma_f32_16x16x32_bf16(t0, *(short8v*)&w3f[(0 * 4 + jt) * 512 + l * 8], acc, 0, 0, 0);
        acc = __builtin_amdgcn_mfma_f32_16x16x32_bf16(t1, *(short8v*)&w3f[(1 * 4 + jt) * 512 + l * 8], acc, 0, 0, 0);
#pragma unroll
        for (int r = 0; r < 4; ++r) {
            int n = nbase + (l >> 4) * 4 + r;
            if (n < n_nodes) out[(size_t)n * 64 + jt * 16 + (l & 15)] = f2bf(acc[r]);
        }
    }
}

// ====== MFMA fused final: T = relu(in@W4+b4); logits = T@Wf+bf; out = log_softmax ======

__global__ __launch_bounds__(256) void mfma_w4final_kernel(const u16* __restrict__ in,
                                                           const float* __restrict__ W4,
                                                           const float* __restrict__ b4,
                                                           const float* __restrict__ Wf,
                                                           const float* __restrict__ bfin,
                                                           float* __restrict__ out, int n_nodes) {
    __shared__ u16 w4f[4096];
    __shared__ u16 wff[3072];
    __shared__ u16 sT[64 * 72];
    __shared__ float sLog[64 * 40];
    const int tid = threadIdx.x;
    for (int idx = tid; idx < 4096; idx += 256) {
        int frag = idx >> 9;
        int within = idx & 511;
        int lane = within >> 3;
        int i = within & 7;
        int kt = frag >> 2, jt = frag & 3;
        int k = kt * 32 + (lane >> 4) * 8 + i;
        int j = jt * 16 + (lane & 15);
        w4f[idx] = f2bf(W4[k * 64 + j]);
    }
    for (int idx = tid; idx < 3072; idx += 256) {
        int frag = idx >> 9;
        int within = idx & 511;
        int lane = within >> 3;
        int i = within & 7;
        int kt = frag / 3, jt = frag % 3;
        int k = kt * 32 + (lane >> 4) * 8 + i;
        int j = jt * 16 + (lane & 15);
        wff[idx] = (j < 40) ? f2bf(Wf[k * 40 + j]) : (u16)0;
    }
    __syncthreads();
    const int w = tid >> 6, l = tid & 63;
    const int nbase = blockIdx.x * 64 + w * 16;
    const int arow = min(nbase + (l & 15), n_nodes - 1);
    short8v a0 = *(const short8v*)&in[(size_t)arow * 64 + (l >> 4) * 8];
    short8v a1 = *(const short8v*)&in[(size_t)arow * 64 + 32 + (l >> 4) * 8];
#pragma unroll
    for (int jt = 0; jt < 4; ++jt) {
        float bv = b4[jt * 16 + (l & 15)];
        float4v acc = {bv, bv, bv, bv};
        acc = __builtin_amdgcn_mfma_f32_16x16x32_bf16(a0, *(short8v*)&w4f[(0 * 4 + jt) * 512 + l * 8], acc, 0, 0, 0);
        acc = __builtin_amdgcn_mfma_f32_16x16x32_bf16(a1, *(short8v*)&w4f[(1 * 4 + jt) * 512 + l * 8], acc, 0, 0, 0);
#pragma unroll
        for (int r = 0; r < 4; ++r) {
            int row = w * 16 + (l >> 4) * 4 + r;
            sT[row * 72 + jt * 16 + (l & 15)] = f2bf(fmaxf(acc[r], 0.f));
        }
    }
    __syncthreads();
    const int trow = w * 16 + (l & 15);
    short8v t0 = *(short8v*)&sT[trow * 72 + (l >> 4) * 8];
    short8v t1 = *(short8v*)&sT[trow * 72 + 32 + (l >> 4) * 8];
#pragma unroll
    for (int jt = 0; jt < 3; ++jt) {
        int col = jt * 16 + (l & 15);
        float bv = (col < 40) ? bfin[col] : 0.f;
        float4v acc = {bv, bv, bv, bv};
        acc = __builtin_amdgcn_mfma_f32_16x16x32_bf16(t0, *(short8v*)&wff[(0 * 3 + jt) * 512 + l * 8], acc, 0, 0, 0);
        acc = __builtin_amdgcn_mfma_f32_16x16x32_bf16(t1, *(short8v*)&wff[(1 * 3 + jt) * 512 + l * 8], acc, 0, 0, 0);
#pragma unroll
        for (int r = 0; r < 4; ++r) {
            int row = w * 16 + (l >> 4) * 4 + r;
            if (col < 40) sLog[row * 40 + col] = acc[r];
        }
    }
    __syncthreads();
    if (tid < 64) {
        const int nl = tid;
        const int n = blockIdx.x * 64 + nl;
        if (n < n_nodes) {
            float m = -1e30f;
            for (int j = 0; j < 40; ++j) m = fmaxf(m, sLog[nl * 40 + j]);
            float s = 0.f;
            for (int j = 0; j < 40; ++j) s += expf(sLog[nl * 40 + j] - m);
            float lse = m + logf(s);
            for (int j = 0; j < 40; j += 4) {
                float4 o;
                o.x = sLog[nl * 40 + j + 0] - lse;
                o.y = sLog[nl * 40 + j + 1] - lse;
                o.z = sLog[nl * 40 + j + 2] - lse;
                o.w = sLog[nl * 40 + j + 3] - lse;
                *(float4*)&out[(size_t)n * 40 + j] = o;
            }
        }
    }
}

// ============================ launch ============================

extern "C" void kernel_launch(void* const* d_in, const int* in_sizes, int n_in,
                              void* d_out, int out_size, void* d_ws, size_t ws_size,
                              hipStream_t stream) {
    const float* x  = (const float*)d_in[0];
    const int*   ei = (const int*)d_in[1];
    const float* W1 = (const float*)d_in[2];
    const float* b1 = (const float*)d_in[3];
    const float* W2 = (const float*)d_in[4];
    const float* b2 = (const float*)d_in[5];
    const float* W3 = (const float*)d_in[6];
    const float* b3 = (const float*)d_in[7];
    const float* W4 = (const float*)d_in[8];
    const float* b4 = (const float*)d_in[9];
    const float* Wf = (const float*)d_in[10];
    const float* bf = (const float*)d_in[11];
    float* outp = (float*)d_out;

    const int N = N_NODES_C, E = N_EDGES_C;
    const int* srcp = ei;
    const int* dstp = ei + E;

    // workspace layout (~52.9 MB)
    char* ws = (char*)d_ws;
    int*          offs  = (int*)(ws);                     // N+1 ints        -> 400128
    int*          boffs = (int*)(ws + 400128);            // NB+1 ints       -> 403328
    int*          bsums = (int*)(ws + 403328);            // 512 ints        -> 405376
    int*          cnt   = (int*)(ws + 405376);            // NB*NBLK ints    -> 1628672
    unsigned int* stage = (unsigned int*)(ws + 1628672);  // E u32           -> 14428672
    int*          srcs  = (int*)(ws + 14428672);          // E ints          -> 27228672
    u16*          Ybf   = (u16*)(ws + 27228672);          // N*64 bf16       -> 40028672
    u16*          F2bf  = (u16*)(ws + 40028672);          // N*64 bf16       -> 52828672

    // ---- cooperative CSR build (hist+scan+boffs+scatter in one launch) ----
    {
        int E_val = E;
        void* args[] = {(void*)&srcp, (void*)&dstp, (void*)&cnt, (void*)&bsums,
                        (void*)&boffs, (void*)&offs, (void*)&stage, (void*)&E_val};
        hipLaunchCooperativeKernel((void*)csr_coop_kernel, dim3(NBLK), dim3(256), args, 0, stream);
    }
    bucket_finalize_kernel<<<NB, 256, 0, stream>>>(stage, boffs, offs, srcs);

    const int mlp_grid = (N + 63) / 64;
    const int gat_grid = (N + 3) / 4;

    // ---- conv1: y = bf16(x@W1); h1 = bf16(relu(y_n + sum y_src + b1)); u = bf16(relu(h1@W2+b2)@W3) ----
    mfma_dense128_kernel<<<mlp_grid, 256, 0, stream>>>(x, W1, Ybf, N);
    gather64v_kernel<<<gat_grid, 256, 0, stream>>>(Ybf, offs, srcs, b1, F2bf, N);
    mfma_w2w3_kernel<<<mlp_grid, 256, 0, stream>>>(F2bf, W2, b2, W3, Ybf, N);

    // ---- conv2: h3 = bf16(relu(u_n + sum u_src + b3)); out = logsoftmax(relu(h3@W4+b4)@Wf + bf) ----
    gather64v_kernel<<<gat_grid, 256, 0, stream>>>(Ybf, offs, srcs, b3, F2bf, N);
    mfma_w4final_kernel<<<mlp_grid, 256, 0, stream>>>(F2bf, W4, b4, Wf, bf, outp, N);
}

// Round 15
// 254.192 us; speedup vs baseline: 1.7681x; 1.7681x over previous
//
#include <hip/hip_runtime.h>
#include <math.h>

#define N_NODES_C 100000
#define N_EDGES_C 3200000
#define NB 782        // ceil(100000 / 128) buckets of 128 nodes
#define BNODES 128
#define LDS_CAP 6144  // per-bucket LDS staging capacity (mean ~4092, +32 sigma)
#define CHUNK 8192    // edges per partition block
#define NBLK 391      // ceil(N_EDGES_C / CHUNK)

typedef unsigned short u16;
typedef __attribute__((ext_vector_type(8))) short short8v;   // 8 bf16 = 4 VGPR
typedef __attribute__((ext_vector_type(4))) float float4v;   // mfma accumulator

__device__ __forceinline__ float bf2f(u16 u) {
    unsigned int t = ((unsigned int)u) << 16;
    return __uint_as_float(t);
}
__device__ __forceinline__ u16 f2bf(float f) {  // round-to-nearest-even
    unsigned int x = __float_as_uint(f);
    x += 0x7fffu + ((x >> 16) & 1u);
    return (u16)(x >> 16);
}

// ============================ atomic-free bucketed partition ============================

__global__ __launch_bounds__(256) void passA_hist_kernel(const int* __restrict__ dst,
                                                         int* __restrict__ cnt, int n_edges) {
    __shared__ int h[NB];
    for (int i = threadIdx.x; i < NB; i += 256) h[i] = 0;
    __syncthreads();
    const int blk = blockIdx.x;
    const int e0 = blk * CHUNK;
    const int cntE = min(CHUNK, n_edges - e0);
    for (int i = threadIdx.x * 4; i < cntE; i += 1024) {
        int4 d4 = *(const int4*)&dst[e0 + i];
        atomicAdd(&h[d4.x >> 7], 1); atomicAdd(&h[d4.y >> 7], 1);
        atomicAdd(&h[d4.z >> 7], 1); atomicAdd(&h[d4.w >> 7], 1);
    }
    __syncthreads();
    for (int i = threadIdx.x; i < NB; i += 256) cnt[i * NBLK + blk] = h[i];
}

__global__ __launch_bounds__(256) void scan_chunks_kernel(int* __restrict__ a, int n, int* __restrict__ bsums) {
    __shared__ int s[256];
    const int tid = threadIdx.x;
    int base = blockIdx.x * 1024 + tid * 4;
    int v[4];
#pragma unroll
    for (int i = 0; i < 4; ++i) v[i] = (base + i < n) ? a[base + i] : 0;
    int tsum = v[0] + v[1] + v[2] + v[3];
    s[tid] = tsum;
    __syncthreads();
    for (int off = 1; off < 256; off <<= 1) {
        int t = (tid >= off) ? s[tid - off] : 0;
        __syncthreads();
        s[tid] += t;
        __syncthreads();
    }
    int run = s[tid] - tsum;
#pragma unroll
    for (int i = 0; i < 4; ++i) {
        run += v[i];
        if (base + i < n) a[base + i] = run;
    }
    if (tid == 255) bsums[blockIdx.x] = s[255];
}

// exclusive scan of bsums[0..nb), nb <= 512, single block of 512
__global__ __launch_bounds__(512) void scan_sums_kernel(int* __restrict__ bsums, int nb) {
    __shared__ int s[512];
    const int tid = threadIdx.x;
    int v = (tid < nb) ? bsums[tid] : 0;
    s[tid] = v;
    __syncthreads();
    for (int off = 1; off < 512; off <<= 1) {
        int t = (tid >= off) ? s[tid - off] : 0;
        __syncthreads();
        s[tid] += t;
        __syncthreads();
    }
    if (tid < nb) bsums[tid] = s[tid] - v;
}

__global__ __launch_bounds__(256) void scan_add_kernel(int* __restrict__ a, int n, const int* __restrict__ bsums) {
    int base = blockIdx.x * 1024 + threadIdx.x * 4;
    int add = bsums[blockIdx.x];
#pragma unroll
    for (int i = 0; i < 4; ++i)
        if (base + i < n) a[base + i] += add;
}

__global__ __launch_bounds__(1024) void boffs_kernel(const int* __restrict__ incl,
                                                     int* __restrict__ boffs,
                                                     int* __restrict__ offs) {
    const int b = threadIdx.x;
    if (b < NB) boffs[b] = b ? incl[b * NBLK - 1] : 0;
    if (b == 0) {
        int total = incl[NB * NBLK - 1];
        boffs[NB] = total;
        offs[N_NODES_C] = total;
    }
}

// pass B (LDS sort, no dst staging): counting sort by bucket, then burst-write each run
__global__ __launch_bounds__(256) void passB_sort_kernel(const int* __restrict__ src,
                                                         const int* __restrict__ dst,
                                                         const int* __restrict__ incl,
                                                         unsigned int* __restrict__ stage,
                                                         int n_edges) {
    __shared__ unsigned int spack[CHUNK];   // 32 KB
    __shared__ int hist[NB];
    __shared__ int lcur[NB];
    __shared__ int tsum[256];
    const int blk = blockIdx.x, tid = threadIdx.x;
    const int e0 = blk * CHUNK;
    const int cntE = min(CHUNK, n_edges - e0);

    for (int b = tid; b < NB; b += 256) hist[b] = 0;
    __syncthreads();

    for (int i = tid * 4; i < cntE; i += 1024) {
        int4 d4 = *(const int4*)&dst[e0 + i];
        atomicAdd(&hist[d4.x >> 7], 1); atomicAdd(&hist[d4.y >> 7], 1);
        atomicAdd(&hist[d4.z >> 7], 1); atomicAdd(&hist[d4.w >> 7], 1);
    }
    __syncthreads();

    {
        int loc[4];
        const int bi = tid * 4;
        int s = 0;
#pragma unroll
        for (int k = 0; k < 4; ++k) {
            int idx = bi + k;
            loc[k] = (idx < NB) ? hist[idx] : 0;
            s += loc[k];
        }
        tsum[tid] = s;
        __syncthreads();
        for (int off = 1; off < 256; off <<= 1) {
            int t = (tid >= off) ? tsum[tid - off] : 0;
            __syncthreads();
            tsum[tid] += t;
            __syncthreads();
        }
        int run = tsum[tid] - s;
#pragma unroll
        for (int k = 0; k < 4; ++k) {
            int idx = bi + k;
            if (idx < NB) {
                int h = loc[k];
                hist[idx] = run;
                lcur[idx] = run;
                run += h;
            }
        }
    }
    __syncthreads();

    for (int i = tid * 4; i < cntE; i += 1024) {
        int4 d4 = *(const int4*)&dst[e0 + i];
        int4 s4 = *(const int4*)&src[e0 + i];
        int p;
        p = atomicAdd(&lcur[d4.x >> 7], 1); spack[p] = (unsigned)s4.x | (((unsigned)d4.x & 127u) << 17);
        p = atomicAdd(&lcur[d4.y >> 7], 1); spack[p] = (unsigned)s4.y | (((unsigned)d4.y & 127u) << 17);
        p = atomicAdd(&lcur[d4.z >> 7], 1); spack[p] = (unsigned)s4.z | (((unsigned)d4.z & 127u) << 17);
        p = atomicAdd(&lcur[d4.w >> 7], 1); spack[p] = (unsigned)s4.w | (((unsigned)d4.w & 127u) << 17);
    }
    __syncthreads();

    for (int b = tid; b < NB; b += 256) {
        int l0 = hist[b];
        int l1 = (b + 1 < NB) ? hist[b + 1] : cntE;
        int idx = b * NBLK + blk;
        int g0 = idx ? incl[idx - 1] : 0;
        for (int j = l0; j < l1; ++j) stage[g0 + (j - l0)] = spack[j];
    }
}

__global__ __launch_bounds__(256) void bucket_finalize_kernel(const unsigned int* __restrict__ stage,
                                                              const int* __restrict__ boffs,
                                                              int* __restrict__ offs,
                                                              int* __restrict__ srcs) {
    __shared__ int hist[BNODES];
    __shared__ int excl[BNODES];
    __shared__ int curs[BNODES];
    __shared__ int sbuf[LDS_CAP];
    const int b = blockIdx.x, tid = threadIdx.x;
    const int base = boffs[b];
    const int count = boffs[b + 1] - base;
    const int n0 = b * BNODES;
    for (int i = tid; i < BNODES; i += 256) hist[i] = 0;
    __syncthreads();
    for (int i = tid; i < count; i += 256) {
        unsigned int w = stage[base + i];
        atomicAdd(&hist[w >> 17], 1);
    }
    __syncthreads();
    if (tid < BNODES) excl[tid] = hist[tid];
    __syncthreads();
    for (int off = 1; off < BNODES; off <<= 1) {
        int t = 0;
        if (tid < BNODES && tid >= off) t = excl[tid - off];
        __syncthreads();
        if (tid < BNODES) excl[tid] += t;
        __syncthreads();
    }
    if (tid < BNODES) {
        int ex = excl[tid] - hist[tid];
        int n = n0 + tid;
        if (n < N_NODES_C) offs[n] = base + ex;
        curs[tid] = ex;
    }
    __syncthreads();
    if (count <= LDS_CAP) {
        for (int i = tid; i < count; i += 256) {
            unsigned int w = stage[base + i];
            int p = atomicAdd(&curs[w >> 17], 1);
            sbuf[p] = (int)(w & 0x1FFFFu);
        }
        __syncthreads();
        for (int i = tid; i < count; i += 256) srcs[base + i] = sbuf[i];
    } else {
        for (int i = tid; i < count; i += 256) {
            unsigned int w = stage[base + i];
            int p = atomicAdd(&curs[w >> 17], 1);
            srcs[base + p] = (int)(w & 0x1FFFFu);
        }
    }
}

// ====== gather64v: bf16 in, bf16 out; 16 lanes/row, 4 row-slots/wave, 32-row unroll ======

__global__ __launch_bounds__(256) void gather64v_kernel(const u16* __restrict__ feat,
                                                        const int* __restrict__ offs,
                                                        const int* __restrict__ srcs,
                                                        const float* __restrict__ bias,
                                                        u16* __restrict__ out, int n_nodes) {
    const int wave = threadIdx.x >> 6;
    const int lane = threadIdx.x & 63;
    const int grp  = lane >> 4;
    const int cl   = lane & 15;
    const int n = blockIdx.x * 4 + wave;
    if (n >= n_nodes) return;

    float a0 = 0.f, a1 = 0.f, a2 = 0.f, a3 = 0.f;
    if (grp == 0) {
        ushort4 v = *(const ushort4*)&feat[(size_t)n * 64 + cl * 4];
        a0 = bf2f(v.x); a1 = bf2f(v.y); a2 = bf2f(v.z); a3 = bf2f(v.w);
    }
    const int s0 = offs[n], s1 = offs[n + 1];
    int i = s0;
    for (; i + 32 <= s1; i += 32) {
        int r[8];
#pragma unroll
        for (int u = 0; u < 8; ++u) r[u] = srcs[i + u * 4 + grp];
        ushort4 v[8];
#pragma unroll
        for (int u = 0; u < 8; ++u) v[u] = *(const ushort4*)&feat[(size_t)r[u] * 64 + cl * 4];
#pragma unroll
        for (int u = 0; u < 8; ++u) {
            a0 += bf2f(v[u].x); a1 += bf2f(v[u].y); a2 += bf2f(v[u].z); a3 += bf2f(v[u].w);
        }
    }
    for (; i + 8 <= s1; i += 8) {
        int ra = srcs[i + grp];
        int rb = srcs[i + 4 + grp];
        ushort4 va = *(const ushort4*)&feat[(size_t)ra * 64 + cl * 4];
        ushort4 vb = *(const ushort4*)&feat[(size_t)rb * 64 + cl * 4];
        a0 += bf2f(va.x); a1 += bf2f(va.y); a2 += bf2f(va.z); a3 += bf2f(va.w);
        a0 += bf2f(vb.x); a1 += bf2f(vb.y); a2 += bf2f(vb.z); a3 += bf2f(vb.w);
    }
    for (; i + 4 <= s1; i += 4) {
        int rr = srcs[i + grp];
        ushort4 v = *(const ushort4*)&feat[(size_t)rr * 64 + cl * 4];
        a0 += bf2f(v.x); a1 += bf2f(v.y); a2 += bf2f(v.z); a3 += bf2f(v.w);
    }
    if (i + grp < s1) {
        int rr = srcs[i + grp];
        ushort4 v = *(const ushort4*)&feat[(size_t)rr * 64 + cl * 4];
        a0 += bf2f(v.x); a1 += bf2f(v.y); a2 += bf2f(v.z); a3 += bf2f(v.w);
    }
    a0 += __shfl_xor(a0, 16); a1 += __shfl_xor(a1, 16);
    a2 += __shfl_xor(a2, 16); a3 += __shfl_xor(a3, 16);
    a0 += __shfl_xor(a0, 32); a1 += __shfl_xor(a1, 32);
    a2 += __shfl_xor(a2, 32); a3 += __shfl_xor(a3, 32);
    if (lane < 16) {
        float4 b = *(const float4*)&bias[cl * 4];
        ushort4 o;
        o.x = f2bf(fmaxf(a0 + b.x, 0.f));
        o.y = f2bf(fmaxf(a1 + b.y, 0.f));
        o.z = f2bf(fmaxf(a2 + b.z, 0.f));
        o.w = f2bf(fmaxf(a3 + b.w, 0.f));
        *(ushort4*)&out[(size_t)n * 64 + cl * 4] = o;
    }
}

// ====== MFMA dense128: out_bf16 = bf16(x) @ bf16(W1)  (W1 frags in LDS; x converted in-reg) ======
// A-fragment: lane l, elem i <- A[l&15][kt*32+(l>>4)*8+i]; D: row=(l>>4)*4+r, col=l&15

__global__ __launch_bounds__(256) void mfma_dense128_kernel(const float* __restrict__ in,
                                                            const float* __restrict__ W,
                                                            u16* __restrict__ out, int n_nodes) {
    __shared__ u16 w1f[16 * 512];   // 16 frags (kt 0..3, jt 0..3) x 512, 16 KB
    const int tid = threadIdx.x;
    for (int idx = tid; idx < 8192; idx += 256) {
        int frag = idx >> 9;          // kt*4+jt
        int within = idx & 511;
        int lane = within >> 3;
        int i = within & 7;
        int kt = frag >> 2, jt = frag & 3;
        int k = kt * 32 + (lane >> 4) * 8 + i;
        int j = jt * 16 + (lane & 15);
        w1f[idx] = f2bf(W[k * 64 + j]);
    }
    __syncthreads();
    const int w = tid >> 6, l = tid & 63;
    const int nbase = blockIdx.x * 64 + w * 16;
    const int arow = min(nbase + (l & 15), n_nodes - 1);
    short8v a[4];
#pragma unroll
    for (int kt = 0; kt < 4; ++kt) {
        float4 f0 = *(const float4*)&in[(size_t)arow * 128 + kt * 32 + (l >> 4) * 8];
        float4 f1 = *(const float4*)&in[(size_t)arow * 128 + kt * 32 + (l >> 4) * 8 + 4];
        short8v t;
        t[0] = (short)f2bf(f0.x); t[1] = (short)f2bf(f0.y);
        t[2] = (short)f2bf(f0.z); t[3] = (short)f2bf(f0.w);
        t[4] = (short)f2bf(f1.x); t[5] = (short)f2bf(f1.y);
        t[6] = (short)f2bf(f1.z); t[7] = (short)f2bf(f1.w);
        a[kt] = t;
    }
#pragma unroll
    for (int jt = 0; jt < 4; ++jt) {
        float4v acc = {0.f, 0.f, 0.f, 0.f};
#pragma unroll
        for (int kt = 0; kt < 4; ++kt)
            acc = __builtin_amdgcn_mfma_f32_16x16x32_bf16(a[kt], *(short8v*)&w1f[(kt * 4 + jt) * 512 + l * 8], acc, 0, 0, 0);
#pragma unroll
        for (int r = 0; r < 4; ++r) {
            int n = nbase + (l >> 4) * 4 + r;
            if (n < n_nodes) out[(size_t)n * 64 + jt * 16 + (l & 15)] = f2bf(acc[r]);
        }
    }
}

// ====== MFMA fused: T = relu(in@W2+b2); out_bf16 = T@W3 ======

__global__ __launch_bounds__(256) void mfma_w2w3_kernel(const u16* __restrict__ in,
                                                        const float* __restrict__ W2,
                                                        const float* __restrict__ b2,
                                                        const float* __restrict__ W3,
                                                        u16* __restrict__ out, int n_nodes) {
    __shared__ u16 w2f[4096];
    __shared__ u16 w3f[4096];
    __shared__ u16 sT[64 * 72];
    const int tid = threadIdx.x;
    for (int idx = tid; idx < 4096; idx += 256) {
        int frag = idx >> 9;
        int within = idx & 511;
        int lane = within >> 3;
        int i = within & 7;
        int kt = frag >> 2, jt = frag & 3;
        int k = kt * 32 + (lane >> 4) * 8 + i;
        int j = jt * 16 + (lane & 15);
        w2f[idx] = f2bf(W2[k * 64 + j]);
        w3f[idx] = f2bf(W3[k * 64 + j]);
    }
    __syncthreads();
    const int w = tid >> 6, l = tid & 63;
    const int nbase = blockIdx.x * 64 + w * 16;
    const int arow = min(nbase + (l & 15), n_nodes - 1);
    short8v a0 = *(const short8v*)&in[(size_t)arow * 64 + (l >> 4) * 8];
    short8v a1 = *(const short8v*)&in[(size_t)arow * 64 + 32 + (l >> 4) * 8];
#pragma unroll
    for (int jt = 0; jt < 4; ++jt) {
        float bv = b2[jt * 16 + (l & 15)];
        float4v acc = {bv, bv, bv, bv};
        acc = __builtin_amdgcn_mfma_f32_16x16x32_bf16(a0, *(short8v*)&w2f[(0 * 4 + jt) * 512 + l * 8], acc, 0, 0, 0);
        acc = __builtin_amdgcn_mfma_f32_16x16x32_bf16(a1, *(short8v*)&w2f[(1 * 4 + jt) * 512 + l * 8], acc, 0, 0, 0);
#pragma unroll
        for (int r = 0; r < 4; ++r) {
            int row = w * 16 + (l >> 4) * 4 + r;
            sT[row * 72 + jt * 16 + (l & 15)] = f2bf(fmaxf(acc[r], 0.f));
        }
    }
    __syncthreads();
    const int trow = w * 16 + (l & 15);
    short8v t0 = *(short8v*)&sT[trow * 72 + (l >> 4) * 8];
    short8v t1 = *(short8v*)&sT[trow * 72 + 32 + (l >> 4) * 8];
#pragma unroll
    for (int jt = 0; jt < 4; ++jt) {
        float4v acc = {0.f, 0.f, 0.f, 0.f};
        acc = __builtin_amdgcn_mfma_f32_16x16x32_bf16(t0, *(short8v*)&w3f[(0 * 4 + jt) * 512 + l * 8], acc, 0, 0, 0);
        acc = __builtin_amdgcn_mfma_f32_16x16x32_bf16(t1, *(short8v*)&w3f[(1 * 4 + jt) * 512 + l * 8], acc, 0, 0, 0);
#pragma unroll
        for (int r = 0; r < 4; ++r) {
            int n = nbase + (l >> 4) * 4 + r;
            if (n < n_nodes) out[(size_t)n * 64 + jt * 16 + (l & 15)] = f2bf(acc[r]);
        }
    }
}

// ====== MFMA fused final: T = relu(in@W4+b4); logits = T@Wf+bf; out = log_softmax ======

__global__ __launch_bounds__(256) void mfma_w4final_kernel(const u16* __restrict__ in,
                                                           const float* __restrict__ W4,
                                                           const float* __restrict__ b4,
                                                           const float* __restrict__ Wf,
                                                           const float* __restrict__ bfin,
                                                           float* __restrict__ out, int n_nodes) {
    __shared__ u16 w4f[4096];
    __shared__ u16 wff[3072];
    __shared__ u16 sT[64 * 72];
    __shared__ float sLog[64 * 40];
    const int tid = threadIdx.x;
    for (int idx = tid; idx < 4096; idx += 256) {
        int frag = idx >> 9;
        int within = idx & 511;
        int lane = within >> 3;
        int i = within & 7;
        int kt = frag >> 2, jt = frag & 3;
        int k = kt * 32 + (lane >> 4) * 8 + i;
        int j = jt * 16 + (lane & 15);
        w4f[idx] = f2bf(W4[k * 64 + j]);
    }
    for (int idx = tid; idx < 3072; idx += 256) {
        int frag = idx >> 9;
        int within = idx & 511;
        int lane = within >> 3;
        int i = within & 7;
        int kt = frag / 3, jt = frag % 3;
        int k = kt * 32 + (lane >> 4) * 8 + i;
        int j = jt * 16 + (lane & 15);
        wff[idx] = (j < 40) ? f2bf(Wf[k * 40 + j]) : (u16)0;
    }
    __syncthreads();
    const int w = tid >> 6, l = tid & 63;
    const int nbase = blockIdx.x * 64 + w * 16;
    const int arow = min(nbase + (l & 15), n_nodes - 1);
    short8v a0 = *(const short8v*)&in[(size_t)arow * 64 + (l >> 4) * 8];
    short8v a1 = *(const short8v*)&in[(size_t)arow * 64 + 32 + (l >> 4) * 8];
#pragma unroll
    for (int jt = 0; jt < 4; ++jt) {
        float bv = b4[jt * 16 + (l & 15)];
        float4v acc = {bv, bv, bv, bv};
        acc = __builtin_amdgcn_mfma_f32_16x16x32_bf16(a0, *(short8v*)&w4f[(0 * 4 + jt) * 512 + l * 8], acc, 0, 0, 0);
        acc = __builtin_amdgcn_mfma_f32_16x16x32_bf16(a1, *(short8v*)&w4f[(1 * 4 + jt) * 512 + l * 8], acc, 0, 0, 0);
#pragma unroll
        for (int r = 0; r < 4; ++r) {
            int row = w * 16 + (l >> 4) * 4 + r;
            sT[row * 72 + jt * 16 + (l & 15)] = f2bf(fmaxf(acc[r], 0.f));
        }
    }
    __syncthreads();
    const int trow = w * 16 + (l & 15);
    short8v t0 = *(short8v*)&sT[trow * 72 + (l >> 4) * 8];
    short8v t1 = *(short8v*)&sT[trow * 72 + 32 + (l >> 4) * 8];
#pragma unroll
    for (int jt = 0; jt < 3; ++jt) {
        int col = jt * 16 + (l & 15);
        float bv = (col < 40) ? bfin[col] : 0.f;
        float4v acc = {bv, bv, bv, bv};
        acc = __builtin_amdgcn_mfma_f32_16x16x32_bf16(t0, *(short8v*)&wff[(0 * 3 + jt) * 512 + l * 8], acc, 0, 0, 0);
        acc = __builtin_amdgcn_mfma_f32_16x16x32_bf16(t1, *(short8v*)&wff[(1 * 3 + jt) * 512 + l * 8], acc, 0, 0, 0);
#pragma unroll
        for (int r = 0; r < 4; ++r) {
            int row = w * 16 + (l >> 4) * 4 + r;
            if (col < 40) sLog[row * 40 + col] = acc[r];
        }
    }
    __syncthreads();
    if (tid < 64) {
        const int nl = tid;
        const int n = blockIdx.x * 64 + nl;
        if (n < n_nodes) {
            float m = -1e30f;
            for (int j = 0; j < 40; ++j) m = fmaxf(m, sLog[nl * 40 + j]);
            float s = 0.f;
            for (int j = 0; j < 40; ++j) s += expf(sLog[nl * 40 + j] - m);
            float lse = m + logf(s);
            for (int j = 0; j < 40; j += 4) {
                float4 o;
                o.x = sLog[nl * 40 + j + 0] - lse;
                o.y = sLog[nl * 40 + j + 1] - lse;
                o.z = sLog[nl * 40 + j + 2] - lse;
                o.w = sLog[nl * 40 + j + 3] - lse;
                *(float4*)&out[(size_t)n * 40 + j] = o;
            }
        }
    }
}

// ============================ launch ============================

extern "C" void kernel_launch(void* const* d_in, const int* in_sizes, int n_in,
                              void* d_out, int out_size, void* d_ws, size_t ws_size,
                              hipStream_t stream) {
    const float* x  = (const float*)d_in[0];
    const int*   ei = (const int*)d_in[1];
    const float* W1 = (const float*)d_in[2];
    const float* b1 = (const float*)d_in[3];
    const float* W2 = (const float*)d_in[4];
    const float* b2 = (const float*)d_in[5];
    const float* W3 = (const float*)d_in[6];
    const float* b3 = (const float*)d_in[7];
    const float* W4 = (const float*)d_in[8];
    const float* b4 = (const float*)d_in[9];
    const float* Wf = (const float*)d_in[10];
    const float* bf = (const float*)d_in[11];
    float* outp = (float*)d_out;

    const int N = N_NODES_C, E = N_EDGES_C;
    const int* srcp = ei;
    const int* dstp = ei + E;

    // workspace layout (~52.9 MB)
    char* ws = (char*)d_ws;
    int*          offs  = (int*)(ws);                     // N+1 ints        -> 400128
    int*          boffs = (int*)(ws + 400128);            // NB+1 ints       -> 403328
    int*          bsums = (int*)(ws + 403328);            // 512 ints        -> 405376
    int*          cnt   = (int*)(ws + 405376);            // NB*NBLK ints    -> 1628672
    unsigned int* stage = (unsigned int*)(ws + 1628672);  // E u32           -> 14428672
    int*          srcs  = (int*)(ws + 14428672);          // E ints          -> 27228672
    u16*          Ybf   = (u16*)(ws + 27228672);          // N*64 bf16       -> 40028672
    u16*          F2bf  = (u16*)(ws + 40028672);          // N*64 bf16       -> 52828672

    // ---- atomic-free bucketed CSR build ----
    passA_hist_kernel<<<NBLK, 256, 0, stream>>>(dstp, cnt, E);
    const int n_scan = NB * NBLK;
    const int nblk_scan = (n_scan + 1023) / 1024;
    scan_chunks_kernel<<<nblk_scan, 256, 0, stream>>>(cnt, n_scan, bsums);
    scan_sums_kernel<<<1, 512, 0, stream>>>(bsums, nblk_scan);
    scan_add_kernel<<<nblk_scan, 256, 0, stream>>>(cnt, n_scan, bsums);
    boffs_kernel<<<1, 1024, 0, stream>>>(cnt, boffs, offs);
    passB_sort_kernel<<<NBLK, 256, 0, stream>>>(srcp, dstp, cnt, stage, E);
    bucket_finalize_kernel<<<NB, 256, 0, stream>>>(stage, boffs, offs, srcs);

    const int mlp_grid = (N + 63) / 64;
    const int gat_grid = (N + 3) / 4;

    // ---- conv1: y = bf16(x@W1); h1 = bf16(relu(y_n + sum y_src + b1)); u = bf16(relu(h1@W2+b2)@W3) ----
    mfma_dense128_kernel<<<mlp_grid, 256, 0, stream>>>(x, W1, Ybf, N);
    gather64v_kernel<<<gat_grid, 256, 0, stream>>>(Ybf, offs, srcs, b1, F2bf, N);
    mfma_w2w3_kernel<<<mlp_grid, 256, 0, stream>>>(F2bf, W2, b2, W3, Ybf, N);

    // ---- conv2: h3 = bf16(relu(u_n + sum u_src + b3)); out = logsoftmax(relu(h3@W4+b4)@Wf + bf) ----
    gather64v_kernel<<<gat_grid, 256, 0, stream>>>(Ybf, offs, srcs, b3, F2bf, N);
    mfma_w4final_kernel<<<mlp_grid, 256, 0, stream>>>(F2bf, W4, b4, Wf, bf, outp, N);
}